// Round 18
// baseline (125.225 us; speedup 1.0000x reference)
//
#include <hip/hip_runtime.h>
#include <math.h>

#define NDIMS 32
#define NANG 496          // 32*31/2
#define MPB 4             // matrices per gen_R block (128 threads)
#define TCOLS 128         // columns per pipeline tile

typedef float f32x4 __attribute__((ext_vector_type(4)));
typedef float f32x2 __attribute__((ext_vector_type(2)));

// async 16B/lane global -> LDS (dest: wave-uniform base, HW adds lane*16;
// src: per-lane address)
__device__ __forceinline__ void load16_to_lds(const float* gsrc, float* ldst) {
    __builtin_amdgcn_global_load_lds(
        (const __attribute__((address_space(1))) void*)gsrc,
        (__attribute__((address_space(3))) void*)ldst,
        16, 0, 0);
}

// ---------------- Kernel 1: build R^T (mus folded) into workspace ----------
// RTbuf[m][k][i] = mus[m][i] * R[i][k]   ([k][i] layout)
__global__ __launch_bounds__(128)
void gen_R(const float* __restrict__ angles, const float* __restrict__ mus,
           float* __restrict__ RT)
{
    __shared__ float2 cs[MPB][NANG];      // 15872 B
    const int tid = threadIdx.x;
    const int m0  = blockIdx.x * MPB;

    for (int idx = tid; idx < MPB * NANG; idx += 128) {
        const int lm = idx / NANG, a = idx - lm * NANG;
        float sv, cv;
        sincosf(angles[(size_t)(m0 + lm) * NANG + a], &sv, &cv);
        cs[lm][a] = make_float2(cv, sv);
    }
    __syncthreads();

    const int lm = tid >> 5, j = tid & 31;   // lane j owns column j of mat[m]
    const int m  = m0 + lm;

    float r[NDIMS];
    #pragma unroll
    for (int i = 0; i < NDIMS; ++i) r[i] = (i == j) ? 1.0f : 0.0f;

    int sidx = 0;
    #pragma unroll
    for (int t = 0; t < NDIMS - 1; ++t) {
        #pragma unroll
        for (int b = t + 1; b < NDIMS; ++b) {
            const float2 v = cs[lm][sidx]; ++sidx;   // compile-time sidx
            const float c = v.x, sn = v.y;
            const float vt = r[t], vb = r[b];
            const float u  = sn * (vt + vb);
            r[t] = (c + sn) * vt - u;
            r[b] = (c - sn) * vb + u;
        }
    }

    // RT[m][k=j][i] = r[i] * mu[i]
    float* dst = RT + (size_t)m * (NDIMS * NDIMS) + (size_t)j * NDIMS;
    const float* mu = mus + (size_t)m * NDIMS;
    #pragma unroll
    for (int i = 0; i < NDIMS; i += 4) {
        f32x4 v;
        v.x = r[i + 0] * mu[i + 0];
        v.y = r[i + 1] * mu[i + 1];
        v.z = r[i + 2] * mu[i + 2];
        v.w = r[i + 3] * mu[i + 3];
        *reinterpret_cast<f32x4*>(dst + i) = v;
    }
}

// ---------------- Kernel 2: persistent, counted-vmcnt double-buffer --------
// R14-R17 post-mortem: every stage->__syncthreads->compute variant plateaus
// at 114-121us regardless of LDS instr count / occupancy / VALU count. The
// shared mechanism is __syncthreads' s_waitcnt vmcnt(0): each block drains
// its whole staging queue once per tile and eats the last load's HBM latency.
// T3/T4 minimum recipe: persistent block per m, double-buffered xt; per iter
// issue stage(t+1), wait a COUNTED vmcnt (stage(t+1)'s loads stay in flight
// across the barrier), raw s_barrier, compute(t), raw s_barrier. vmcnt N per
// wave (in-order retire): t=0 -> 4 (prologue rt+stage0 = 5 oldest, keep 4
// newest); steady -> 12 (queue = [4 loads t+1][8 stores t][4 loads t+2],
// oldest 4 = loads(t+1)); tail -> 8 ([4 loads][8 stores], no new issue).
// Buffer safety: stage(t+2) writes buf[t&1], issued only after the second
// barrier of iter t (all waves done reading buf[t&1]). Compute = R15's best
// (r8 x c2, v_pk_fma_f32, 3 LDS reads/k/wave).
__global__ __launch_bounds__(256, 4)
void apply_P1(const float* __restrict__ x, const float* __restrict__ RT,
              float* __restrict__ out, int S)
{
    __shared__ float rt[NDIMS * NDIMS];       // [k][i], 4 KB
    __shared__ float xt[2][NDIMS][TCOLS];     // 2 x 16 KB

    const int tid  = threadIdx.x;
    const int m    = blockIdx.x;
    const int wid  = tid >> 6;                // wave id, 0..3
    const int lane = tid & 63;

    const float* __restrict__ xm = x   + (size_t)m * NDIMS * S;
    float*       __restrict__ om = out + (size_t)m * NDIMS * S;

    // prologue: rt (1 gload_lds/wave) + stage tile 0 (4 gload_lds/wave).
    // Lane-split: one width-16 instr = 1KB = TWO 512B rows (lanes 32-63
    // land at dest+512B = row k+1); src = xm + (k + (lane>>5))*S + (lane&31)*4.
    load16_to_lds(RT + (size_t)m * (NDIMS * NDIMS) + wid * 256 + lane * 4,
                  &rt[wid * 256]);

    const size_t srcRow = (size_t)(lane >> 5) * S + (lane & 31) * 4;
    #pragma unroll
    for (int p = 0; p < 4; ++p) {
        const int k = wid * 8 + p * 2;
        load16_to_lds(xm + (size_t)k * S + srcRow, &xt[0][k][0]);
    }

    const int i0 = wid * 8;                   // this wave's 8 output rows
    const int NT = S / TCOLS;                 // 16 for S=2048

    for (int t = 0; t < NT; ++t) {
        const int cb = t & 1;

        // issue next tile's staging into the opposite buffer, then wait
        // ONLY for the current tile's loads (counted vmcnt, in-order retire)
        if (t + 1 < NT) {
            const float* src = xm + (size_t)(t + 1) * TCOLS + srcRow;
            #pragma unroll
            for (int p = 0; p < 4; ++p) {
                const int k = wid * 8 + p * 2;
                load16_to_lds(src + (size_t)k * S, &xt[cb ^ 1][k][0]);
            }
            if (t == 0) {
                asm volatile("s_waitcnt vmcnt(4)" ::: "memory");
            } else {
                asm volatile("s_waitcnt vmcnt(12)" ::: "memory");
            }
        } else {
            asm volatile("s_waitcnt vmcnt(8)" ::: "memory");
        }
        __builtin_amdgcn_s_barrier();         // all waves: tile t resident

        // compute tile t from buf cb: 8 rows x 2 cols per thread
        f32x2 acc[8];
        #pragma unroll
        for (int r = 0; r < 8; ++r) acc[r] = (f32x2)0.0f;

        #pragma unroll 2
        for (int k = 0; k < NDIMS; ++k) {
            const f32x2 xv = *reinterpret_cast<const f32x2*>(&xt[cb][k][lane * 2]);    // lane-unique b64
            const f32x4 ra = *reinterpret_cast<const f32x4*>(&rt[k * NDIMS + i0]);     // broadcast b128
            const f32x4 rb = *reinterpret_cast<const f32x4*>(&rt[k * NDIMS + i0 + 4]); // broadcast b128
            acc[0] += ra.x * xv;   // v_pk_fma_f32
            acc[1] += ra.y * xv;
            acc[2] += ra.z * xv;
            acc[3] += ra.w * xv;
            acc[4] += rb.x * xv;
            acc[5] += rb.y * xv;
            acc[6] += rb.z * xv;
            acc[7] += rb.w * xv;
        }

        // store tile t: per row, wave writes 512B contiguous; nontemporal
        float* ob = om + (size_t)t * TCOLS + lane * 2;
        #pragma unroll
        for (int r = 0; r < 8; ++r)
            __builtin_nontemporal_store(acc[r],
                reinterpret_cast<f32x2*>(ob + (size_t)(i0 + r) * S));

        // all waves done reading buf[cb] before next iter overwrites it
        __builtin_amdgcn_s_barrier();
    }
}

// ---------------- Fallback: fused kernel (odd sizes / tiny ws) -------------
#define RT_STRIDE 36
__global__ __launch_bounds__(256, 4)
void soot_fused(const float* __restrict__ x, const float* __restrict__ angles,
                const float* __restrict__ mus, float* __restrict__ out, int S)
{
    __shared__ float2 cs[NANG];
    __shared__ float  RT[NDIMS * RT_STRIDE];
    const int tid = threadIdx.x;
    const int m   = blockIdx.x;

    for (int s0 = tid; s0 < NANG; s0 += 256) {
        float sv, cv;
        sincosf(angles[(size_t)m * NANG + s0], &sv, &cv);
        cs[s0] = make_float2(cv, sv);
    }
    __syncthreads();

    if (tid < NDIMS) {
        const int j = tid;
        float r[NDIMS];
        #pragma unroll
        for (int i = 0; i < NDIMS; ++i) r[i] = (i == j) ? 1.0f : 0.0f;
        int sidx = 0;
        #pragma unroll
        for (int t = 0; t < NDIMS - 1; ++t)
            #pragma unroll
            for (int b = t + 1; b < NDIMS; ++b) {
                const float2 v = cs[sidx]; ++sidx;
                const float c = v.x, sn = v.y;
                const float vt = r[t], vb = r[b];
                const float u  = sn * (vt + vb);
                r[t] = (c + sn) * vt - u;
                r[b] = (c - sn) * vb + u;
            }
        #pragma unroll
        for (int i = 0; i < NDIMS; ++i)
            RT[j * RT_STRIDE + i] = r[i] * mus[(size_t)m * NDIMS + i];
    }
    __syncthreads();

    for (int c0 = tid; c0 < S; c0 += 256) {
        float acc[NDIMS];
        #pragma unroll
        for (int i = 0; i < NDIMS; ++i) acc[i] = 0.f;
        #pragma unroll
        for (int k = 0; k < NDIMS; ++k) {
            const float xv = x[(size_t)m * NDIMS * S + (size_t)k * S + c0];
            #pragma unroll
            for (int i = 0; i < NDIMS; ++i)
                acc[i] = fmaf(RT[k * RT_STRIDE + i], xv, acc[i]);
        }
        #pragma unroll
        for (int i = 0; i < NDIMS; ++i)
            out[(size_t)m * NDIMS * S + (size_t)i * S + c0] = acc[i];
    }
}

extern "C" void kernel_launch(void* const* d_in, const int* in_sizes, int n_in,
                              void* d_out, int out_size, void* d_ws, size_t ws_size,
                              hipStream_t stream) {
    const float* x      = (const float*)d_in[0];
    const float* angles = (const float*)d_in[1];
    const float* mus    = (const float*)d_in[2];
    float* out          = (float*)d_out;

    const int M = in_sizes[1] / NANG;              // 1024
    const int S = in_sizes[0] / (M * NDIMS);       // 2048

    const size_t rt_bytes = (size_t)M * NDIMS * NDIMS * sizeof(float);  // 4 MB
    if (ws_size >= rt_bytes && (M % MPB) == 0 && (S % TCOLS) == 0 && S / TCOLS >= 2) {
        float* RT = (float*)d_ws;
        gen_R<<<dim3(M / MPB), 128, 0, stream>>>(angles, mus, RT);
        apply_P1<<<dim3(M), 256, 0, stream>>>(x, RT, out, S);
    } else {
        soot_fused<<<dim3(M), 256, 0, stream>>>(x, angles, mus, out, S);
    }
}